// Round 6
// baseline (2547.640 us; speedup 1.0000x reference)
//
#include <hip/hip_runtime.h>
#include <stdint.h>

typedef __attribute__((ext_vector_type(8))) short bf16x8;
typedef __attribute__((ext_vector_type(4))) float f32x4;
typedef unsigned short u16;

#define NBATCH 4
#define SEQ    4096
#define CIN    512
#define HD     64
#define OC     576      // CIN + HD (f32 elements per out row)
#define NROW   (NBATCH * SEQ)
#define ROWU   1152     // u16 slots per out row (576 f32 * 2)

// q/k/v carve: u16 (bf16) scratch inside each out row's x-byte region
// (u16 indices 0..191 of the row = f32 cols 0..95, overwritten by copyx last).
#define QOFF 0
#define KOFF 64
#define VOFF 128

__device__ __forceinline__ float b2f(u16 u) {
    union { uint32_t i; float f; } w; w.i = ((uint32_t)u) << 16; return w.f;
}
__device__ __forceinline__ u16 f2b(float f) {
    union { float f; uint32_t i; } w; w.f = f;
    uint32_t r = w.i + 0x7fffu + ((w.i >> 16) & 1u);
    return (u16)(r >> 16);
}

// ---------------------------------------------------------------------------
// Kernel 1: QKV projection via MFMA 16x16x32 bf16. Inputs are FLOAT32
// (established: rounds 2-5 bit-identical => all took the f32 path).
// B-fragments loaded directly from Wq/Wk/Wv (strided f32). q/k/v written as
// bf16 u16 into the carve slots of each out row. No d_ws usage.
// ---------------------------------------------------------------------------
__global__ __launch_bounds__(256) void proj(
    const float* __restrict__ x,
    const float* __restrict__ Wq, const float* __restrict__ Wk, const float* __restrict__ Wv,
    const float* __restrict__ bq, const float* __restrict__ bk, const float* __restrict__ bv,
    u16* __restrict__ ou)        // d_out viewed as u16 (carve only)
{
    int lane = threadIdx.x & 63, wid = threadIdx.x >> 6;
    int m = lane & 15, quad = lane >> 4;
    int wg = blockIdx.x * 4 + wid;   // 0..1023
    int r0 = wg * 16;                // global row (n*SEQ + t)

    f32x4 acc[12];
#pragma unroll
    for (int i = 0; i < 12; i++) acc[i] = (f32x4){0.f, 0.f, 0.f, 0.f};

    const float* xp = x + (size_t)(r0 + m) * CIN + quad * 8;

    for (int c = 0; c < 16; c++) {
        // A fragment: x[row = r0+m][k = c*32 + quad*8 + j], f32 -> bf16
        f32x4 lo = *(const f32x4*)(xp + c * 32);
        f32x4 hi = *(const f32x4*)(xp + c * 32 + 4);
        bf16x8 a;
#pragma unroll
        for (int j = 0; j < 4; j++) { a[j] = (short)f2b(lo[j]); a[4 + j] = (short)f2b(hi[j]); }
#pragma unroll
        for (int nt = 0; nt < 12; nt++) {
            const float* W = (nt < 4) ? Wq : (nt < 8) ? Wk : Wv;
            int col = (nt & 3) * 16 + m;      // output column within the 64
            bf16x8 b;
#pragma unroll
            for (int j = 0; j < 8; j++)
                b[j] = (short)f2b(W[(size_t)(c * 32 + quad * 8 + j) * HD + col]);
            acc[nt] = __builtin_amdgcn_mfma_f32_16x16x32_bf16(a, b, acc[nt], 0, 0, 0);
        }
    }

    // writeback into carve: C/D layout row = quad*4+reg, col = m
#pragma unroll
    for (int nt = 0; nt < 4; nt++) {
        int bi = nt * 16 + m;
        float biasq = bq[bi], biask = bk[bi], biasv = bv[bi];
#pragma unroll
        for (int reg = 0; reg < 4; reg++) {
            size_t r = (size_t)(r0 + quad * 4 + reg);
            ou[r * ROWU + QOFF + bi] = f2b(acc[nt][reg] + biasq);
            ou[r * ROWU + KOFF + bi] = f2b(acc[4 + nt][reg] + biask);
            ou[r * ROWU + VOFF + bi] = f2b(acc[8 + nt][reg] + biasv);
        }
    }
}

// ---------------------------------------------------------------------------
// Kernel 2: MFMA-free reference attention (two-pass softmax), q/k/v from the
// carve, FLOAT32 stores to out[:, 512:576]. One wave per query row.
// ---------------------------------------------------------------------------
__global__ __launch_bounds__(256) void attn_simple(
    const u16* __restrict__ ou, float* __restrict__ out)
{
    int lane = threadIdx.x & 63, wid = threadIdx.x >> 6;
    int b = blockIdx.x;                  // 0..4095
    int batch = b >> 10;
    int t = (b & 1023) + wid * 1024;     // row within batch
    const float SCALE = 0.125f;          // 1/sqrt(64)

    size_t base = (size_t)batch * SEQ;

    float qf[64];
    const u16* qrow = ou + (base + t) * ROWU + QOFF;
#pragma unroll
    for (int d = 0; d < 64; d++) qf[d] = b2f(qrow[d]);

    int nb = (t >> 6) + 1;               // key blocks

    // ---- pass 1: row max ----
    float mrow = -1e30f;
    for (int kb = 0; kb < nb; kb++) {
        int s = kb * 64 + lane;
        float L = -1e30f;
        if (s <= t) {
            const u16* krow = ou + (base + s) * ROWU + KOFF;
            float acc = 0.f;
#pragma unroll
            for (int d = 0; d < 64; d++) acc += qf[d] * b2f(krow[d]);
            L = acc * SCALE;
        }
        mrow = fmaxf(mrow, L);
    }
#pragma unroll
    for (int off = 1; off < 64; off <<= 1)
        mrow = fmaxf(mrow, __shfl_xor(mrow, off, 64));

    // ---- pass 2: l and o (o for dim d = lane) ----
    float l = 0.f, o = 0.f;
    for (int kb = 0; kb < nb; kb++) {
        int s = kb * 64 + lane;
        float p = 0.f;
        if (s <= t) {
            const u16* krow = ou + (base + s) * ROWU + KOFF;
            float acc = 0.f;
#pragma unroll
            for (int d = 0; d < 64; d++) acc += qf[d] * b2f(krow[d]);
            p = __expf(acc * SCALE - mrow);
        }
        l += p;
        int smax = min(64, t - kb * 64 + 1);
        const u16* vblk = ou + (base + kb * 64) * ROWU + VOFF + lane;
        for (int key = 0; key < smax; key++) {
            float pk = __shfl(p, key, 64);
            o += pk * b2f(vblk[(size_t)key * ROWU]);
        }
    }
#pragma unroll
    for (int off = 1; off < 64; off <<= 1)
        l += __shfl_xor(l, off, 64);

    out[(base + t) * OC + CIN + lane] = o / l;   // FLOAT32 store
}

// ---------------------------------------------------------------------------
// Kernel 3: out[:, :512] = x (f32 -> f32 exact copy), overwriting the carve.
// One block per row; lane covers 8 consecutive f32 columns.
// ---------------------------------------------------------------------------
__global__ __launch_bounds__(64) void copyx(const float* __restrict__ x, float* __restrict__ out)
{
    int lane = threadIdx.x;
    size_t r = blockIdx.x;
    const float* xp = x + r * CIN + lane * 8;
    float* op = out + r * OC + lane * 8;
    f32x4 lo = *(const f32x4*)(xp);
    f32x4 hi = *(const f32x4*)(xp + 4);
    *(f32x4*)(op)     = lo;
    *(f32x4*)(op + 4) = hi;
}

// ---------------------------------------------------------------------------
extern "C" void kernel_launch(void* const* d_in, const int* in_sizes, int n_in,
                              void* d_out, int out_size, void* d_ws, size_t ws_size,
                              hipStream_t stream) {
    const float* x  = (const float*)d_in[0];
    const float* Wq = (const float*)d_in[1];
    const float* bq = (const float*)d_in[2];
    const float* Wk = (const float*)d_in[3];
    const float* bk = (const float*)d_in[4];
    const float* Wv = (const float*)d_in[5];
    const float* bv = (const float*)d_in[6];
    float* out = (float*)d_out;      // FLOAT32 output (reference dtype)
    u16* ou = (u16*)d_out;           // u16 view for the q/k/v carve

    (void)d_ws; (void)ws_size; (void)in_sizes; (void)n_in; (void)out_size;

    proj<<<dim3(256), dim3(256), 0, stream>>>(x, Wq, Wk, Wv, bq, bk, bv, ou);
    attn_simple<<<dim3(4096), dim3(256), 0, stream>>>(ou, out);
    copyx<<<dim3(NROW), dim3(64), 0, stream>>>(x, out);
}

// Round 7
// 206.523 us; speedup vs baseline: 12.3359x; 12.3359x over previous
//
#include <hip/hip_runtime.h>
#include <stdint.h>

typedef __attribute__((ext_vector_type(8))) short bf16x8;
typedef __attribute__((ext_vector_type(4))) float f32x4;
typedef __attribute__((ext_vector_type(4))) unsigned short u16x4;
typedef unsigned short u16;

#define NBATCH 4
#define SEQ    4096
#define CIN    512
#define HD     64
#define OC     576      // f32 elements per out row
#define NROW   (NBATCH * SEQ)

__device__ __forceinline__ float b2f(u16 u) {
    union { uint32_t i; float f; } w; w.i = ((uint32_t)u) << 16; return w.f;
}
__device__ __forceinline__ u16 f2b(float f) {
    union { float f; uint32_t i; } w; w.f = f;
    uint32_t r = w.i + 0x7fffu + ((w.i >> 16) & 1u);
    return (u16)(r >> 16);
}

// ---------------------------------------------------------------------------
// Kernel 1: transpose f32 weights into bf16 wt[192][512] in ws
// (rows 0-63 = Wq^T, 64-127 = Wk^T, 128-191 = Wv^T).
// ---------------------------------------------------------------------------
__global__ void prep_wt(const float* __restrict__ Wq, const float* __restrict__ Wk,
                        const float* __restrict__ Wv, u16* __restrict__ wt) {
    int row = blockIdx.x;            // 0..191
    int g = row >> 6, j = row & 63;
    const float* W = (g == 0) ? Wq : (g == 1) ? Wk : Wv;
    for (int k = threadIdx.x; k < CIN; k += blockDim.x)
        wt[row * CIN + k] = f2b(W[k * HD + j]);
}

// ---------------------------------------------------------------------------
// Kernel 2: QKV projection via MFMA 16x16x32 bf16 + fused f32 x-copy.
// Wave: 16 rows x 192 cols, K=512. out[:, :512] = x stored from the same
// f32 registers used for A-frags. q,k row-major bf16 [16384][64];
// v transposed vt[n][64][4096] bf16.
// ---------------------------------------------------------------------------
__global__ __launch_bounds__(256) void proj(
    const float* __restrict__ x, const u16* __restrict__ wt,
    const float* __restrict__ bq, const float* __restrict__ bk, const float* __restrict__ bv,
    u16* __restrict__ qb, u16* __restrict__ kbuf, u16* __restrict__ vtb,
    float* __restrict__ out)
{
    int lane = threadIdx.x & 63, wid = threadIdx.x >> 6;
    int m = lane & 15, quad = lane >> 4;
    int wg = blockIdx.x * 4 + wid;   // 0..1023
    int r0 = wg * 16;                // global row (n*SEQ + t)

    f32x4 acc[12];
#pragma unroll
    for (int i = 0; i < 12; i++) acc[i] = (f32x4){0.f, 0.f, 0.f, 0.f};

    const float* xp = x + (size_t)(r0 + m) * CIN + quad * 8;
    float* op = out + (size_t)(r0 + m) * OC + quad * 8;

    for (int c = 0; c < 16; c++) {
        f32x4 lo = *(const f32x4*)(xp + c * 32);
        f32x4 hi = *(const f32x4*)(xp + c * 32 + 4);
        *(f32x4*)(op + c * 32)     = lo;       // exact f32 x-copy
        *(f32x4*)(op + c * 32 + 4) = hi;
        bf16x8 a;
#pragma unroll
        for (int j = 0; j < 4; j++) { a[j] = (short)f2b(lo[j]); a[4 + j] = (short)f2b(hi[j]); }
#pragma unroll
        for (int nt = 0; nt < 12; nt++) {
            bf16x8 b = *(const bf16x8*)(wt + (size_t)(nt * 16 + m) * CIN + c * 32 + quad * 8);
            acc[nt] = __builtin_amdgcn_mfma_f32_16x16x32_bf16(a, b, acc[nt], 0, 0, 0);
        }
    }

    int n  = r0 >> 12;          // batch
    int tl = r0 & (SEQ - 1);    // t within batch

    // q (nt 0-3), k (nt 4-7): row-major [row][64]; C/D: row=quad*4+reg, col=m
#pragma unroll
    for (int nt = 0; nt < 4; nt++) {
        int bi = nt * 16 + m;
        float biasq = bq[bi], biask = bk[bi];
#pragma unroll
        for (int reg = 0; reg < 4; reg++) {
            size_t r = (size_t)(r0 + quad * 4 + reg);
            qb[r * HD + bi]   = f2b(acc[nt][reg] + biasq);
            kbuf[r * HD + bi] = f2b(acc[4 + nt][reg] + biask);
        }
    }
    // v (nt 8-11): transposed vt[n][vcol][t], 4 consecutive t packed (8B)
#pragma unroll
    for (int nt = 0; nt < 4; nt++) {
        int bi = nt * 16 + m;
        float biasv = bv[bi];
        u16x4 pk;
#pragma unroll
        for (int reg = 0; reg < 4; reg++) pk[reg] = f2b(acc[8 + nt][reg] + biasv);
        u16* vp = vtb + (size_t)(n * HD + bi) * SEQ + tl + quad * 4;
        *(u16x4*)vp = pk;
    }
}

// ---------------------------------------------------------------------------
// Kernel 3: causal MFMA flash attention. ONE WAVE per block (64 thr).
// Block b (0..511): batch = b>>7, p = b&127; the wave processes tiles
// j = p and j = 255-p sequentially -> constant ~65 key-block iterations
// per wave (perfect balance). Online softmax in registers (state per
// (quad,reg) = per row, replicated across each 16-lane group).
// P: C-layout -> per-wave LDS (stride 72) -> A-layout. f32 stores.
// ---------------------------------------------------------------------------
__global__ __launch_bounds__(64) void attn(
    const u16* __restrict__ qb, const u16* __restrict__ kbuf,
    const u16* __restrict__ vtb, float* __restrict__ out)
{
    __shared__ short plds[16 * 72];

    int lane = threadIdx.x & 63;
    int m = lane & 15, quad = lane >> 4;
    int blk = blockIdx.x;
    int batch = blk >> 7, p = blk & 127;

    const u16* kp = kbuf + (size_t)(batch * SEQ + m) * HD + quad * 8;  // + s*HD
    const u16* vp = vtb + (size_t)(batch * HD + m) * SEQ + quad * 8;   // + vcol*SEQ + s

    const float SC = 0.125f * 1.44269504088896f;  // scale * log2(e)

    for (int half = 0; half < 2; half++) {
        int j = half ? (255 - p) : p;
        int t0 = j * 16;
        int nkb = (j >> 2) + 1;

        const u16* qp = qb + (size_t)(batch * SEQ + t0 + m) * HD + quad * 8;
        bf16x8 aq0 = *(const bf16x8*)qp;
        bf16x8 aq1 = *(const bf16x8*)(qp + 32);

        float mst[4], lst[4];
        f32x4 o[4];
#pragma unroll
        for (int r = 0; r < 4; r++) { mst[r] = -1e30f; lst[r] = 0.f; }
#pragma unroll
        for (int nt = 0; nt < 4; nt++) o[nt] = (f32x4){0.f, 0.f, 0.f, 0.f};

        // preload K frags for kb = 0
        bf16x8 k0[4], k1[4];
#pragma unroll
        for (int st = 0; st < 4; st++) {
            k0[st] = *(const bf16x8*)(kp + (size_t)(st * 16) * HD);
            k1[st] = *(const bf16x8*)(kp + (size_t)(st * 16) * HD + 32);
        }

        for (int kb = 0; kb < nkb; kb++) {
            int s0 = kb * 64;

            // S = Q K^T : B-frag n=key=st*16+m, k=d
            f32x4 s[4];
#pragma unroll
            for (int st = 0; st < 4; st++) {
                f32x4 a = (f32x4){0.f, 0.f, 0.f, 0.f};
                a = __builtin_amdgcn_mfma_f32_16x16x32_bf16(aq0, k0[st], a, 0, 0, 0);
                a = __builtin_amdgcn_mfma_f32_16x16x32_bf16(aq1, k1[st], a, 0, 0, 0);
                s[st] = a;
            }

            // V loads (current) + K prefetch (next) hide behind softmax VALU
            bf16x8 vf0[4], vf1[4];
#pragma unroll
            for (int nt = 0; nt < 4; nt++) {
                vf0[nt] = *(const bf16x8*)(vp + (size_t)(nt * 16) * SEQ + s0);
                vf1[nt] = *(const bf16x8*)(vp + (size_t)(nt * 16) * SEQ + s0 + 32);
            }
            if (kb + 1 < nkb) {
                int sn = s0 + 64;
#pragma unroll
                for (int st = 0; st < 4; st++) {
                    k0[st] = *(const bf16x8*)(kp + (size_t)(sn + st * 16) * HD);
                    k1[st] = *(const bf16x8*)(kp + (size_t)(sn + st * 16) * HD + 32);
                }
            }

            if (kb == nkb - 1) {
#pragma unroll
                for (int st = 0; st < 4; st++)
#pragma unroll
                    for (int r = 0; r < 4; r++) {
                        int scol = s0 + st * 16 + m;
                        int trow = t0 + quad * 4 + r;
                        s[st][r] = (scol <= trow) ? s[st][r] * SC : -1e30f;
                    }
            } else {
#pragma unroll
                for (int st = 0; st < 4; st++)
#pragma unroll
                    for (int r = 0; r < 4; r++) s[st][r] *= SC;
            }

            // row max across the 16-lane group (rows = (quad, reg))
            float mx[4];
#pragma unroll
            for (int r = 0; r < 4; r++)
                mx[r] = fmaxf(fmaxf(s[0][r], s[1][r]), fmaxf(s[2][r], s[3][r]));
#pragma unroll
            for (int off = 1; off <= 8; off <<= 1)
#pragma unroll
                for (int r = 0; r < 4; r++)
                    mx[r] = fmaxf(mx[r], __shfl_xor(mx[r], off, 64));

            float alpha[4];
#pragma unroll
            for (int r = 0; r < 4; r++) {
                float mn = fmaxf(mst[r], mx[r]);
                alpha[r] = exp2f(mst[r] - mn);
                mst[r] = mn;
            }

            float ls[4];
#pragma unroll
            for (int r = 0; r < 4; r++) {
#pragma unroll
                for (int st = 0; st < 4; st++) s[st][r] = exp2f(s[st][r] - mst[r]);
                ls[r] = (s[0][r] + s[1][r]) + (s[2][r] + s[3][r]);
            }
#pragma unroll
            for (int off = 1; off <= 8; off <<= 1)
#pragma unroll
                for (int r = 0; r < 4; r++)
                    ls[r] += __shfl_xor(ls[r], off, 64);
#pragma unroll
            for (int r = 0; r < 4; r++) lst[r] = lst[r] * alpha[r] + ls[r];
#pragma unroll
            for (int nt = 0; nt < 4; nt++)
#pragma unroll
                for (int r = 0; r < 4; r++) o[nt][r] *= alpha[r];

            // P: C-layout -> LDS -> A-layout (covers rows 0-15 x keys 0-63)
#pragma unroll
            for (int st = 0; st < 4; st++)
#pragma unroll
                for (int r = 0; r < 4; r++)
                    plds[(quad * 4 + r) * 72 + st * 16 + m] = (short)f2b(s[st][r]);

            __asm__ volatile("" ::: "memory");   // no hoisting reads above stores

            bf16x8 p0 = *(const bf16x8*)(plds + m * 72 + quad * 8);
            bf16x8 p1 = *(const bf16x8*)(plds + m * 72 + 32 + quad * 8);

            // O += P V : B-frag n=vcol=nt*16+m, k=key (contiguous via vt)
#pragma unroll
            for (int nt = 0; nt < 4; nt++) {
                o[nt] = __builtin_amdgcn_mfma_f32_16x16x32_bf16(p0, vf0[nt], o[nt], 0, 0, 0);
                o[nt] = __builtin_amdgcn_mfma_f32_16x16x32_bf16(p1, vf1[nt], o[nt], 0, 0, 0);
            }
        }

        // epilogue: normalize, f32 store to out[:, 512:576]
#pragma unroll
        for (int r = 0; r < 4; r++) {
            float inv = 1.0f / lst[r];
            size_t row = (size_t)(batch * SEQ + t0 + quad * 4 + r);
#pragma unroll
            for (int nt = 0; nt < 4; nt++)
                out[row * OC + CIN + nt * 16 + m] = o[nt][r] * inv;
        }
    }
}

// ---------------------------------------------------------------------------
extern "C" void kernel_launch(void* const* d_in, const int* in_sizes, int n_in,
                              void* d_out, int out_size, void* d_ws, size_t ws_size,
                              hipStream_t stream) {
    const float* x  = (const float*)d_in[0];
    const float* Wq = (const float*)d_in[1];
    const float* bq = (const float*)d_in[2];
    const float* Wk = (const float*)d_in[3];
    const float* bk = (const float*)d_in[4];
    const float* Wv = (const float*)d_in[5];
    const float* bv = (const float*)d_in[6];
    float* out = (float*)d_out;

    u16* ws  = (u16*)d_ws;
    u16* wt  = ws;                          // 192*512 elems (pad to 128K)
    u16* qb  = ws + 131072;                 // 16384*64 = 1M elems
    u16* kb  = qb + 16384 * 64;
    u16* vtb = kb + 16384 * 64;             // transposed v: [4][64][4096]

    prep_wt<<<dim3(192), dim3(256), 0, stream>>>(Wq, Wk, Wv, wt);
    proj<<<dim3(256), dim3(256), 0, stream>>>(x, wt, bq, bk, bv, qb, kb, vtb, out);
    attn<<<dim3(512), dim3(64), 0, stream>>>(qb, kb, vtb, out);
}

// Round 8
// 188.533 us; speedup vs baseline: 13.5130x; 1.0954x over previous
//
#include <hip/hip_runtime.h>
#include <stdint.h>

typedef __attribute__((ext_vector_type(8))) short bf16x8;
typedef __attribute__((ext_vector_type(4))) float f32x4;
typedef __attribute__((ext_vector_type(4))) unsigned short u16x4;
typedef unsigned short u16;

#define NBATCH 4
#define SEQ    4096
#define CIN    512
#define HD     64
#define OC     576      // f32 elements per out row
#define NROW   (NBATCH * SEQ)

__device__ __forceinline__ float b2f(u16 u) {
    union { uint32_t i; float f; } w; w.i = ((uint32_t)u) << 16; return w.f;
}
__device__ __forceinline__ u16 f2b(float f) {
    union { float f; uint32_t i; } w; w.f = f;
    uint32_t r = w.i + 0x7fffu + ((w.i >> 16) & 1u);
    return (u16)(r >> 16);
}

// ---------------------------------------------------------------------------
// Kernel 1: transpose f32 weights into bf16 wt[192][512] (unchanged).
// ---------------------------------------------------------------------------
__global__ void prep_wt(const float* __restrict__ Wq, const float* __restrict__ Wk,
                        const float* __restrict__ Wv, u16* __restrict__ wt) {
    int row = blockIdx.x;            // 0..191
    int g = row >> 6, j = row & 63;
    const float* W = (g == 0) ? Wq : (g == 1) ? Wk : Wv;
    for (int k = threadIdx.x; k < CIN; k += blockDim.x)
        wt[row * CIN + k] = f2b(W[k * HD + j]);
}

// ---------------------------------------------------------------------------
// Kernel 2: QKV projection via MFMA + fused f32 x-copy (unchanged from R7).
// ---------------------------------------------------------------------------
__global__ __launch_bounds__(256) void proj(
    const float* __restrict__ x, const u16* __restrict__ wt,
    const float* __restrict__ bq, const float* __restrict__ bk, const float* __restrict__ bv,
    u16* __restrict__ qb, u16* __restrict__ kbuf, u16* __restrict__ vtb,
    float* __restrict__ out)
{
    int lane = threadIdx.x & 63, wid = threadIdx.x >> 6;
    int m = lane & 15, quad = lane >> 4;
    int wg = blockIdx.x * 4 + wid;   // 0..1023
    int r0 = wg * 16;                // global row (n*SEQ + t)

    f32x4 acc[12];
#pragma unroll
    for (int i = 0; i < 12; i++) acc[i] = (f32x4){0.f, 0.f, 0.f, 0.f};

    const float* xp = x + (size_t)(r0 + m) * CIN + quad * 8;
    float* op = out + (size_t)(r0 + m) * OC + quad * 8;

    for (int c = 0; c < 16; c++) {
        f32x4 lo = *(const f32x4*)(xp + c * 32);
        f32x4 hi = *(const f32x4*)(xp + c * 32 + 4);
        *(f32x4*)(op + c * 32)     = lo;       // exact f32 x-copy
        *(f32x4*)(op + c * 32 + 4) = hi;
        bf16x8 a;
#pragma unroll
        for (int j = 0; j < 4; j++) { a[j] = (short)f2b(lo[j]); a[4 + j] = (short)f2b(hi[j]); }
#pragma unroll
        for (int nt = 0; nt < 12; nt++) {
            bf16x8 b = *(const bf16x8*)(wt + (size_t)(nt * 16 + m) * CIN + c * 32 + quad * 8);
            acc[nt] = __builtin_amdgcn_mfma_f32_16x16x32_bf16(a, b, acc[nt], 0, 0, 0);
        }
    }

    int n  = r0 >> 12;          // batch
    int tl = r0 & (SEQ - 1);    // t within batch

#pragma unroll
    for (int nt = 0; nt < 4; nt++) {
        int bi = nt * 16 + m;
        float biasq = bq[bi], biask = bk[bi];
#pragma unroll
        for (int reg = 0; reg < 4; reg++) {
            size_t r = (size_t)(r0 + quad * 4 + reg);
            qb[r * HD + bi]   = f2b(acc[nt][reg] + biasq);
            kbuf[r * HD + bi] = f2b(acc[4 + nt][reg] + biask);
        }
    }
#pragma unroll
    for (int nt = 0; nt < 4; nt++) {
        int bi = nt * 16 + m;
        float biasv = bv[bi];
        u16x4 pk;
#pragma unroll
        for (int reg = 0; reg < 4; reg++) pk[reg] = f2b(acc[8 + nt][reg] + biasv);
        u16* vp = vtb + (size_t)(n * HD + bi) * SEQ + tl + quad * 4;
        *(u16x4*)vp = pk;
    }
}

// ---------------------------------------------------------------------------
// Kernel 3: causal flash attention, TRANSPOSED-S formulation + 4-way key
// split. Block (256 thr = 4 waves) handles tiles p and 255-p sequentially;
// wave w takes key-blocks w, w+4, ... of each tile (balanced ~17 iters).
//
// S^T = K·Q^T via mfma(A=K-frag, B=Q-frag): D col = query = lane&15,
// row = key_local = quad*4+reg. Softmax state (m,l) is ONE scalar per lane
// (its query t0+m): max/sum = in-register tree over 16 regs + shfl 16,32.
// O^T = V^T·P^T: A = vt frag (contiguous), B = P^T from per-wave LDS.
// Partials merged via LDS (flash combine), contiguous f32x4 stores.
// ---------------------------------------------------------------------------
__global__ __launch_bounds__(256, 2) void attn(
    const u16* __restrict__ qb, const u16* __restrict__ kbuf,
    const u16* __restrict__ vtb, float* __restrict__ out)
{
    __shared__ __align__(16) short plds[4][16 * 72];   // P^T per wave
    __shared__ __align__(16) float ldso[4][16][68];    // O^T partials [w][t][v]
    __shared__ float ldsm[4][16];                      // m partials [w][t]
    __shared__ float ldsl[4][16];                      // l partials [w][t]

    int tid = threadIdx.x;
    int lane = tid & 63, w = tid >> 6;
    int m = lane & 15, quad = lane >> 4;
    int blk = blockIdx.x;
    int batch = blk >> 7, p = blk & 127;

    const u16* kp = kbuf + (size_t)(batch * SEQ + m) * HD + quad * 8;  // + s*HD
    const u16* vp = vtb + (size_t)(batch * HD + m) * SEQ + quad * 8;   // + vblk*16*SEQ + s
    const u16* qpb = qb + (size_t)(batch * SEQ + m) * HD + quad * 8;   // + t0*HD

    const float SC = 0.125f * 1.44269504088896f;  // scale * log2(e)
    short* pw = plds[w];

    for (int half = 0; half < 2; half++) {
        int j = half ? (255 - p) : p;
        int t0 = j * 16;
        int nkb = (j >> 2) + 1;

        // Q B-frag (query = lane&15 = m)
        bf16x8 bq0 = *(const bf16x8*)(qpb + (size_t)t0 * HD);
        bf16x8 bq1 = *(const bf16x8*)(qpb + (size_t)t0 * HD + 32);

        float mst = -1e30f, lst = 0.f;
        f32x4 o[4];
#pragma unroll
        for (int nt = 0; nt < 4; nt++) o[nt] = (f32x4){0.f, 0.f, 0.f, 0.f};

        int cnt = (nkb > w) ? ((nkb - w + 3) >> 2) : 0;
        int kb = w;

        // preload K A-frags for first kb (memory-safe even if cnt==0)
        bf16x8 k0[4], k1[4];
#pragma unroll
        for (int st = 0; st < 4; st++) {
            k0[st] = *(const bf16x8*)(kp + (size_t)(kb * 64 + st * 16) * HD);
            k1[st] = *(const bf16x8*)(kp + (size_t)(kb * 64 + st * 16) * HD + 32);
        }

        for (int it = 0; it < cnt; it++, kb += 4) {
            int s0 = kb * 64;

            // S^T = K Q^T (col = query, row = key_local)
            f32x4 s[4];
#pragma unroll
            for (int st = 0; st < 4; st++) {
                f32x4 a = (f32x4){0.f, 0.f, 0.f, 0.f};
                a = __builtin_amdgcn_mfma_f32_16x16x32_bf16(k0[st], bq0, a, 0, 0, 0);
                a = __builtin_amdgcn_mfma_f32_16x16x32_bf16(k1[st], bq1, a, 0, 0, 0);
                s[st] = a;
            }

            // V loads (current block) + K prefetch (next) hide behind softmax
            bf16x8 vf0[4], vf1[4];
#pragma unroll
            for (int nt = 0; nt < 4; nt++) {
                vf0[nt] = *(const bf16x8*)(vp + (size_t)(nt * 16) * SEQ + s0);
                vf1[nt] = *(const bf16x8*)(vp + (size_t)(nt * 16) * SEQ + s0 + 32);
            }
            if (it + 1 < cnt) {
                int sn = s0 + 256;
#pragma unroll
                for (int st = 0; st < 4; st++) {
                    k0[st] = *(const bf16x8*)(kp + (size_t)(sn + st * 16) * HD);
                    k1[st] = *(const bf16x8*)(kp + (size_t)(sn + st * 16) * HD + 32);
                }
            }

            // scale; causal mask only on the diagonal block (kb == nkb-1)
            if (kb == nkb - 1) {
#pragma unroll
                for (int st = 0; st < 4; st++)
#pragma unroll
                    for (int r = 0; r < 4; r++) {
                        int key = s0 + st * 16 + quad * 4 + r;
                        s[st][r] = (key <= t0 + m) ? s[st][r] * SC : -1e30f;
                    }
            } else {
#pragma unroll
                for (int st = 0; st < 4; st++)
#pragma unroll
                    for (int r = 0; r < 4; r++) s[st][r] *= SC;
            }

            // per-query max: in-register tree (16) + cross-quad shfl (2 rounds)
            float mx = -1e30f;
#pragma unroll
            for (int st = 0; st < 4; st++) {
                float a01 = fmaxf(s[st][0], s[st][1]);
                float a23 = fmaxf(s[st][2], s[st][3]);
                mx = fmaxf(mx, fmaxf(a01, a23));
            }
            mx = fmaxf(mx, __shfl_xor(mx, 16, 64));
            mx = fmaxf(mx, __shfl_xor(mx, 32, 64));

            float mn = fmaxf(mst, mx);
            float alpha = exp2f(mst - mn);
            mst = mn;

            // P = 2^(s - m); per-query sum same pattern
            float ls = 0.f;
#pragma unroll
            for (int st = 0; st < 4; st++) {
#pragma unroll
                for (int r = 0; r < 4; r++) s[st][r] = exp2f(s[st][r] - mn);
                ls += (s[st][0] + s[st][1]) + (s[st][2] + s[st][3]);
            }
            ls += __shfl_xor(ls, 16, 64);
            ls += __shfl_xor(ls, 32, 64);
            lst = lst * alpha + ls;
#pragma unroll
            for (int nt = 0; nt < 4; nt++)
#pragma unroll
                for (int r = 0; r < 4; r++) o[nt][r] *= alpha;

            // P^T -> LDS (packed u16x4 per st: consecutive key_local regs)
#pragma unroll
            for (int st = 0; st < 4; st++) {
                u16x4 pk;
#pragma unroll
                for (int r = 0; r < 4; r++) pk[r] = f2b(s[st][r]);
                *(u16x4*)(pw + m * 72 + st * 16 + quad * 4) = pk;
            }
            __asm__ volatile("" ::: "memory");

            // B-frag read: B[n=query=m][k=key=quad*8+j]
            bf16x8 p0 = *(const bf16x8*)(pw + m * 72 + quad * 8);
            bf16x8 p1 = *(const bf16x8*)(pw + m * 72 + 32 + quad * 8);

            // O^T += V^T P^T
#pragma unroll
            for (int nt = 0; nt < 4; nt++) {
                o[nt] = __builtin_amdgcn_mfma_f32_16x16x32_bf16(vf0[nt], p0, o[nt], 0, 0, 0);
                o[nt] = __builtin_amdgcn_mfma_f32_16x16x32_bf16(vf1[nt], p1, o[nt], 0, 0, 0);
            }
        }

        // publish partials: O^T lane holds (t = m, v = nt*16 + quad*4 + r)
        if (quad == 0) { ldsm[w][m] = mst; ldsl[w][m] = lst; }
#pragma unroll
        for (int nt = 0; nt < 4; nt++)
            *(f32x4*)&ldso[w][m][nt * 16 + quad * 4] = o[nt];
        __syncthreads();

        // merge 4 partials: thread tau -> (t = tau>>4, v = (tau&15)*4 .. +3)
        {
            int t = tid >> 4, vg = tid & 15;
            float m0 = ldsm[0][t], m1 = ldsm[1][t], m2 = ldsm[2][t], m3 = ldsm[3][t];
            float mmax = fmaxf(fmaxf(m0, m1), fmaxf(m2, m3));
            float c0 = exp2f(m0 - mmax), c1 = exp2f(m1 - mmax);
            float c2 = exp2f(m2 - mmax), c3 = exp2f(m3 - mmax);
            float L = ldsl[0][t] * c0 + ldsl[1][t] * c1 + ldsl[2][t] * c2 + ldsl[3][t] * c3;
            f32x4 o0 = *(const f32x4*)&ldso[0][t][vg * 4];
            f32x4 o1 = *(const f32x4*)&ldso[1][t][vg * 4];
            f32x4 o2 = *(const f32x4*)&ldso[2][t][vg * 4];
            f32x4 o3 = *(const f32x4*)&ldso[3][t][vg * 4];
            float inv = 1.0f / L;
            f32x4 res;
#pragma unroll
            for (int i = 0; i < 4; i++)
                res[i] = (o0[i] * c0 + o1[i] * c1 + o2[i] * c2 + o3[i] * c3) * inv;
            *(f32x4*)(out + (size_t)(batch * SEQ + t0 + t) * OC + CIN + vg * 4) = res;
        }
        __syncthreads();   // LDS reused for the second tile
    }
}

// ---------------------------------------------------------------------------
extern "C" void kernel_launch(void* const* d_in, const int* in_sizes, int n_in,
                              void* d_out, int out_size, void* d_ws, size_t ws_size,
                              hipStream_t stream) {
    const float* x  = (const float*)d_in[0];
    const float* Wq = (const float*)d_in[1];
    const float* bq = (const float*)d_in[2];
    const float* Wk = (const float*)d_in[3];
    const float* bk = (const float*)d_in[4];
    const float* Wv = (const float*)d_in[5];
    const float* bv = (const float*)d_in[6];
    float* out = (float*)d_out;

    u16* ws  = (u16*)d_ws;
    u16* wt  = ws;                          // 192*512 elems (pad to 128K)
    u16* qb  = ws + 131072;                 // 16384*64 = 1M elems
    u16* kb  = qb + 16384 * 64;
    u16* vtb = kb + 16384 * 64;             // transposed v: [4][64][4096]

    prep_wt<<<dim3(192), dim3(256), 0, stream>>>(Wq, Wk, Wv, wt);
    proj<<<dim3(256), dim3(256), 0, stream>>>(x, wt, bq, bk, bv, qb, kb, vtb, out);
    attn<<<dim3(512), dim3(256), 0, stream>>>(qb, kb, vtb, out);
}